// Round 1
// baseline (112.120 us; speedup 1.0000x reference)
//
#include <hip/hip_runtime.h>

#define NT   24
#define CIN  9
#define NF   32
#define KM   16
#define HID  128
#define NCLS 10
#define SEQ_LEN (NT*CIN)   // 216

__global__ __launch_bounds__(64) void dtwnet_fused(
    const float* __restrict__ x,
    const float* __restrict__ kern,
    const float* __restrict__ W1, const float* __restrict__ b1,
    const float* __restrict__ W2, const float* __restrict__ b2,
    const float* __restrict__ Wl, const float* __restrict__ bl,
    float* __restrict__ out)
{
  __shared__ float klds[CIN*KM*NF];    // [c][i][f] -> lane-consecutive f, conflict-free
  __shared__ float seq_lds[2*SEQ_LEN]; // 2 sequences per block
  __shared__ float feat_lds[2*NF];
  __shared__ float h1_lds[2*HID];
  __shared__ float h2_lds[2*HID];
  __shared__ float logit_lds[2*NCLS];

  const int tid = threadIdx.x;
  const int bid = blockIdx.x;

  // stage filter kernels (transposed) and the block's 2 sequences
  for (int idx = tid; idx < NF*KM*CIN; idx += 64) {
    int f = idx / (KM*CIN);
    int r = idx - f*(KM*CIN);
    int i = r / CIN;
    int c = r - i*CIN;
    klds[(c*KM + i)*NF + f] = kern[idx];
  }
  for (int idx = tid; idx < 2*SEQ_LEN; idx += 64) {
    seq_lds[idx] = x[bid*(2*SEQ_LEN) + idx];
  }
  __syncthreads();

  const int local = tid >> 5;   // which of the 2 sequences
  const int f     = tid & 31;   // filter id
  const float* sq = &seq_lds[local*SEQ_LEN];

  // Forward DTW with fused path-cost tracking:
  //   D = classic DTW accumulated distance
  //   S = sum of local costs C along the path the reference's backtrack
  //       would take (tie-break: diag, then up, then left — np.argmin first-min)
  float prevD[NT], prevS[NT];
  {
    float k[CIN];
    #pragma unroll
    for (int c = 0; c < CIN; ++c) k[c] = klds[(c*KM + 0)*NF + f];
    float run = 0.f;
    #pragma unroll
    for (int j = 0; j < NT; ++j) {
      float cost = 0.f;
      #pragma unroll
      for (int c = 0; c < CIN; ++c) { float d = k[c] - sq[j*CIN+c]; cost = fmaf(d, d, cost); }
      run += cost;            // D[0,j] = cumsum;  S[0,j] = same (forced-left path)
      prevD[j] = run;
      prevS[j] = run;
    }
  }
  for (int i = 1; i < KM; ++i) {
    float k[CIN];
    #pragma unroll
    for (int c = 0; c < CIN; ++c) k[c] = klds[(c*KM + i)*NF + f];
    float Crow[NT];
    #pragma unroll
    for (int j = 0; j < NT; ++j) {
      float cost = 0.f;
      #pragma unroll
      for (int c = 0; c < CIN; ++c) { float d = k[c] - sq[j*CIN+c]; cost = fmaf(d, d, cost); }
      Crow[j] = cost;
    }
    // j = 0: only 'up' predecessor
    float diagD = prevD[0], diagS = prevS[0];
    float nD = Crow[0] + prevD[0];
    float nS = Crow[0] + prevS[0];
    float leftD = nD, leftS = nS;
    prevD[0] = nD; prevS[0] = nS;
    #pragma unroll
    for (int j = 1; j < NT; ++j) {
      float upD = prevD[j], upS = prevS[j];
      float dD = diagD,     dS = diagS;
      float mn = fminf(leftD, fminf(upD, dD));
      float D2 = Crow[j] + mn;
      // np.argmin([diag, up, left]) first-min tie-break:
      bool takeDiag = (dD <= upD) && (dD <= leftD);
      bool takeUp   = (upD <= leftD);
      float predS = takeDiag ? dS : (takeUp ? upS : leftS);
      float S2 = Crow[j] + predS;
      diagD = upD; diagS = upS;       // carry for next column
      prevD[j] = D2; prevS[j] = S2;
      leftD = D2; leftS = S2;
    }
  }
  feat_lds[local*NF + f] = prevS[NT-1];
  __syncthreads();

  // MLP: 32 -> 128 (relu) -> 128 (relu) -> 10 (softmax), 2 seqs per block
  #pragma unroll
  for (int rep = 0; rep < 4; ++rep) {
    int idx = tid + rep*64;        // 0..255
    int sl  = idx >> 7;
    int j   = idx & (HID-1);
    const float* ft = &feat_lds[sl*NF];
    float acc = b1[j];
    #pragma unroll
    for (int k = 0; k < NF; ++k) acc = fmaf(ft[k], W1[k*HID + j], acc);
    h1_lds[idx] = fmaxf(acc, 0.f);
  }
  __syncthreads();
  #pragma unroll
  for (int rep = 0; rep < 4; ++rep) {
    int idx = tid + rep*64;
    int sl  = idx >> 7;
    int j   = idx & (HID-1);
    const float* hh = &h1_lds[sl*HID];
    float acc = b2[j];
    for (int k = 0; k < HID; ++k) acc = fmaf(hh[k], W2[k*HID + j], acc);
    h2_lds[idx] = fmaxf(acc, 0.f);
  }
  __syncthreads();
  if (tid < 2*NCLS) {
    int sl = tid / NCLS;
    int j  = tid - sl*NCLS;
    const float* hh = &h2_lds[sl*HID];
    float acc = bl[j];
    for (int k = 0; k < HID; ++k) acc = fmaf(hh[k], Wl[k*NCLS + j], acc);
    logit_lds[tid] = acc;
  }
  __syncthreads();
  if (tid < 2) {
    const float* lg = &logit_lds[tid*NCLS];
    float mx = lg[0];
    #pragma unroll
    for (int j = 1; j < NCLS; ++j) mx = fmaxf(mx, lg[j]);
    float e[NCLS]; float sum = 0.f;
    #pragma unroll
    for (int j = 0; j < NCLS; ++j) { e[j] = __expf(lg[j] - mx); sum += e[j]; }
    float inv = 1.f / sum;
    float* op = out + (bid*2 + tid)*NCLS;
    #pragma unroll
    for (int j = 0; j < NCLS; ++j) op[j] = e[j] * inv;
  }
}

extern "C" void kernel_launch(void* const* d_in, const int* in_sizes, int n_in,
                              void* d_out, int out_size, void* d_ws, size_t ws_size,
                              hipStream_t stream) {
  const float* x    = (const float*)d_in[0];
  const float* kern = (const float*)d_in[1];
  const float* W1   = (const float*)d_in[2];
  const float* b1   = (const float*)d_in[3];
  const float* W2   = (const float*)d_in[4];
  const float* b2   = (const float*)d_in[5];
  const float* Wl   = (const float*)d_in[6];
  const float* bl   = (const float*)d_in[7];
  float* out = (float*)d_out;

  // 2048 sequences, 2 per block
  dtwnet_fused<<<1024, 64, 0, stream>>>(x, kern, W1, b1, W2, b2, Wl, bl, out);
}

// Round 2
// 106.527 us; speedup vs baseline: 1.0525x; 1.0525x over previous
//
#include <hip/hip_runtime.h>

#define NT   24
#define CIN  9
#define NF   32
#define KM   16
#define HID  128
#define NCLS 10
#define SEQ_LEN (NT*CIN)   // 216
#define PADJ 12            // seq LDS row pitch (floats) -> 16B aligned columns

__global__ __launch_bounds__(64, 1) void dtwnet_fused(
    const float* __restrict__ x,
    const float* __restrict__ kern,
    const float* __restrict__ W1, const float* __restrict__ b1,
    const float* __restrict__ W2, const float* __restrict__ b2,
    const float* __restrict__ Wl, const float* __restrict__ bl,
    float* __restrict__ out)
{
  __shared__ float klds[KM*CIN*NF];        // [(i*9+c)*32 + f]  lane-consecutive f
  __shared__ float seq_lds[2*NT*PADJ];     // [local][j][0..11] padded
  __shared__ float feat_lds[2*NF];
  __shared__ float h1_lds[2*HID];
  __shared__ float h2_lds[2*HID];
  __shared__ float logit_lds[2*NCLS];

  const int tid = threadIdx.x;
  const int bid = blockIdx.x;

  // --- stage kernels transposed: conflict-free LDS writes (consecutive dst),
  //     scattered global reads (18KB total, L1/L2 resident) ---
  for (int d = tid; d < KM*CIN*NF; d += 64) {   // 72 iters
    int f  = d & (NF-1);
    int rc = d >> 5;                 // i*9 + c
    klds[d] = kern[f*(KM*CIN) + rc];
  }
  // --- stage 2 sequences, padded to 12 floats per timestep ---
  for (int d = tid; d < 2*SEQ_LEN; d += 64) {   // 7 iters, coalesced reads
    int local = d / SEQ_LEN;
    int r     = d - local*SEQ_LEN;
    int j     = r / CIN;
    int c     = r - j*CIN;
    seq_lds[local*NT*PADJ + j*PADJ + c] = x[bid*(2*SEQ_LEN) + d];
  }
  __syncthreads();

  const int local = tid >> 5;
  const int f     = tid & 31;
  const float* sl = &seq_lds[local*NT*PADJ];

  // --- filter kernel fully in registers (144 VGPRs) ---
  float kf[KM*CIN];
  #pragma unroll
  for (int r = 0; r < KM*CIN; ++r) kf[r] = klds[r*NF + f];   // conflict-free b32

  // --- column-major DTW with fused path-cost tracking ---
  float pD[KM], pS[KM];   // previous column
  {
    // column 0: only 'up' predecessor -> cumsum down rows
    const float4* sp = (const float4*)sl;
    float4 s0 = sp[0], s1 = sp[1], s2 = sp[2];
    float s[CIN] = {s0.x,s0.y,s0.z,s0.w,s1.x,s1.y,s1.z,s1.w,s2.x};
    float run = 0.f;
    #pragma unroll
    for (int i = 0; i < KM; ++i) {
      float cost = 0.f;
      #pragma unroll
      for (int c = 0; c < CIN; ++c) { float d = kf[i*CIN+c] - s[c]; cost = fmaf(d, d, cost); }
      run += cost;
      pD[i] = run; pS[i] = run;
    }
  }
  #pragma unroll 1
  for (int j = 1; j < NT; ++j) {
    const float4* sp = (const float4*)(sl + j*PADJ);
    float4 s0 = sp[0], s1 = sp[1], s2 = sp[2];
    float s[CIN] = {s0.x,s0.y,s0.z,s0.w,s1.x,s1.y,s1.z,s1.w,s2.x};
    // row 0: left only
    float cost0 = 0.f;
    #pragma unroll
    for (int c = 0; c < CIN; ++c) { float d = kf[c] - s[c]; cost0 = fmaf(d, d, cost0); }
    float upD = cost0 + pD[0];
    float upS = cost0 + pS[0];
    float diagD = pD[0], diagS = pS[0];
    pD[0] = upD; pS[0] = upS;
    #pragma unroll
    for (int i = 1; i < KM; ++i) {
      float cost = 0.f;
      #pragma unroll
      for (int c = 0; c < CIN; ++c) { float d = kf[i*CIN+c] - s[c]; cost = fmaf(d, d, cost); }
      float leftD = pD[i], leftS = pS[i];
      float dD = diagD,    dS = diagS;
      float mn = fminf(dD, fminf(upD, leftD));
      float D2 = cost + mn;
      // np.argmin([diag, up, left]) first-min tie-break
      bool takeDiag = (dD <= upD) && (dD <= leftD);
      bool takeUp   = (upD <= leftD);
      float predS = takeDiag ? dS : (takeUp ? upS : leftS);
      float S2 = cost + predS;
      diagD = leftD; diagS = leftS;   // old pD[i] is row i+1's diagonal
      pD[i] = D2; pS[i] = S2;
      upD = D2; upS = S2;
    }
  }
  feat_lds[local*NF + f] = pS[KM-1];
  __syncthreads();

  // --- MLP: 32 -> 128 relu -> 128 relu -> 10 softmax (2 seqs / block) ---
  #pragma unroll
  for (int rep = 0; rep < 4; ++rep) {
    int idx = tid + rep*64;        // 0..255
    int sl2 = idx >> 7;
    int j   = idx & (HID-1);
    const float* ft = &feat_lds[sl2*NF];
    float acc = b1[j];
    #pragma unroll
    for (int k = 0; k < NF; ++k) acc = fmaf(ft[k], W1[k*HID + j], acc);
    h1_lds[idx] = fmaxf(acc, 0.f);
  }
  __syncthreads();
  #pragma unroll
  for (int rep = 0; rep < 4; ++rep) {
    int idx = tid + rep*64;
    int sl2 = idx >> 7;
    int j   = idx & (HID-1);
    const float4* hh = (const float4*)&h1_lds[sl2*HID];
    float a0 = b2[j], a1 = 0.f, a2 = 0.f, a3 = 0.f;
    #pragma unroll
    for (int k = 0; k < HID/4; ++k) {
      float4 h4 = hh[k];
      a0 = fmaf(h4.x, W2[(4*k+0)*HID + j], a0);
      a1 = fmaf(h4.y, W2[(4*k+1)*HID + j], a1);
      a2 = fmaf(h4.z, W2[(4*k+2)*HID + j], a2);
      a3 = fmaf(h4.w, W2[(4*k+3)*HID + j], a3);
    }
    h2_lds[idx] = fmaxf((a0 + a1) + (a2 + a3), 0.f);
  }
  __syncthreads();
  if (tid < 2*NCLS) {
    int sl2 = tid / NCLS;
    int j   = tid - sl2*NCLS;
    const float4* hh = (const float4*)&h2_lds[sl2*HID];
    float a0 = bl[j], a1 = 0.f, a2 = 0.f, a3 = 0.f;
    #pragma unroll
    for (int k = 0; k < HID/4; ++k) {
      float4 h4 = hh[k];
      a0 = fmaf(h4.x, Wl[(4*k+0)*NCLS + j], a0);
      a1 = fmaf(h4.y, Wl[(4*k+1)*NCLS + j], a1);
      a2 = fmaf(h4.z, Wl[(4*k+2)*NCLS + j], a2);
      a3 = fmaf(h4.w, Wl[(4*k+3)*NCLS + j], a3);
    }
    logit_lds[tid] = (a0 + a1) + (a2 + a3);
  }
  __syncthreads();
  if (tid < 2) {
    const float* lg = &logit_lds[tid*NCLS];
    float mx = lg[0];
    #pragma unroll
    for (int j = 1; j < NCLS; ++j) mx = fmaxf(mx, lg[j]);
    float e[NCLS]; float sum = 0.f;
    #pragma unroll
    for (int j = 0; j < NCLS; ++j) { e[j] = __expf(lg[j] - mx); sum += e[j]; }
    float inv = 1.f / sum;
    float* op = out + (bid*2 + tid)*NCLS;
    #pragma unroll
    for (int j = 0; j < NCLS; ++j) op[j] = e[j] * inv;
  }
}

extern "C" void kernel_launch(void* const* d_in, const int* in_sizes, int n_in,
                              void* d_out, int out_size, void* d_ws, size_t ws_size,
                              hipStream_t stream) {
  const float* x    = (const float*)d_in[0];
  const float* kern = (const float*)d_in[1];
  const float* W1   = (const float*)d_in[2];
  const float* b1   = (const float*)d_in[3];
  const float* W2   = (const float*)d_in[4];
  const float* b2   = (const float*)d_in[5];
  const float* Wl   = (const float*)d_in[6];
  const float* bl   = (const float*)d_in[7];
  float* out = (float*)d_out;

  dtwnet_fused<<<1024, 64, 0, stream>>>(x, kern, W1, b1, W2, b2, Wl, bl, out);
}

// Round 3
// 103.213 us; speedup vs baseline: 1.0863x; 1.0321x over previous
//
#include <hip/hip_runtime.h>

#define NT   24
#define CIN  9
#define NF   32
#define KM   16
#define HID  128
#define NCLS 10
#define SEQ_LEN (NT*CIN)   // 216
#define PADJ 12            // seq LDS row pitch (floats) -> 16B aligned columns
#define KSTRIDE 148        // floats per filter in klds; 148*4=592B (16B-aligned, odd-ish bank stride)
#define RSTRIP 8           // rows per strip (2 strips of 8 = KM)

// DP strip: processes rows [STRIP*8, STRIP*8+8) over all 24 columns.
// rowD/rowS carry the previous column's values for the strip's 8 rows.
// bnd[j*64+tid] carries the strip-boundary (row 7) D,S per column (thread-private).
template<int STRIP>
__device__ __forceinline__ void dp_strip(const float* __restrict__ klds_f, // &klds[f*KSTRIDE]
                                         const float* __restrict__ sl,     // this seq's LDS base
                                         float2* __restrict__ bnd, int tid,
                                         float (&rowD)[RSTRIP], float (&rowS)[RSTRIP])
{
  // --- kernel strip -> registers (18 x b128, scalarized) ---
  float kf[RSTRIP*CIN];
  {
    const float4* kb = (const float4*)(klds_f + STRIP*RSTRIP*CIN);
    #pragma unroll
    for (int q = 0; q < 18; ++q) {
      float4 t = kb[q];
      kf[4*q+0] = t.x; kf[4*q+1] = t.y; kf[4*q+2] = t.z; kf[4*q+3] = t.w;
    }
  }

  // --- column 0: up-only chain (cumsum down) ---
  {
    const float4* sp = (const float4*)sl;
    float4 s0 = sp[0], s1 = sp[1], s2 = sp[2];
    float s[CIN] = {s0.x,s0.y,s0.z,s0.w,s1.x,s1.y,s1.z,s1.w,s2.x};
    float accD, accS;
    if (STRIP == 0) { accD = 0.f; accS = 0.f; }
    else            { float2 b = bnd[tid]; accD = b.x; accS = b.y; }
    #pragma unroll
    for (int i = 0; i < RSTRIP; ++i) {
      float cost = 0.f;
      #pragma unroll
      for (int c = 0; c < CIN; ++c) { float d = kf[i*CIN+c] - s[c]; cost = fmaf(d, d, cost); }
      accD += cost; accS += cost;
      rowD[i] = accD; rowS[i] = accS;
    }
    if (STRIP == 0) bnd[tid] = make_float2(rowD[RSTRIP-1], rowS[RSTRIP-1]);
  }

  // --- columns 1..23 ---
  float bPrevD = 0.f, bPrevS = 0.f;
  if (STRIP == 1) { float2 b = bnd[tid]; bPrevD = b.x; bPrevS = b.y; }

  #pragma unroll 2
  for (int j = 1; j < NT; ++j) {
    const float4* sp = (const float4*)(sl + j*PADJ);
    float4 s0 = sp[0], s1 = sp[1], s2 = sp[2];
    float s[CIN] = {s0.x,s0.y,s0.z,s0.w,s1.x,s1.y,s1.z,s1.w,s2.x};

    float upD, upS, diagD, diagS;
    // cell 0 of the strip
    {
      float cost = 0.f;
      #pragma unroll
      for (int c = 0; c < CIN; ++c) { float d = kf[c] - s[c]; cost = fmaf(d, d, cost); }
      if (STRIP == 0) {
        // global row 0: left-only (cumsum)
        float nD = cost + rowD[0], nS = cost + rowS[0];
        diagD = rowD[0]; diagS = rowS[0];
        rowD[0] = nD; rowS[0] = nS; upD = nD; upS = nS;
      } else {
        float2 bcur = bnd[j*64 + tid];
        float leftD = rowD[0], leftS = rowS[0];
        float dD = bPrevD, dS = bPrevS, uD = bcur.x, uS = bcur.y;
        float mn = fminf(dD, fminf(uD, leftD));
        float D2 = cost + mn;
        bool tD = (dD <= uD) && (dD <= leftD);
        bool tU = (uD <= leftD);
        float pS = tD ? dS : (tU ? uS : leftS);
        float S2 = cost + pS;
        diagD = leftD; diagS = leftS;
        rowD[0] = D2; rowS[0] = S2; upD = D2; upS = S2;
        bPrevD = bcur.x; bPrevS = bcur.y;
      }
    }
    // cells 1..7 of the strip
    #pragma unroll
    for (int i = 1; i < RSTRIP; ++i) {
      float cost = 0.f;
      #pragma unroll
      for (int c = 0; c < CIN; ++c) { float d = kf[i*CIN+c] - s[c]; cost = fmaf(d, d, cost); }
      float leftD = rowD[i], leftS = rowS[i];
      float mn = fminf(diagD, fminf(upD, leftD));
      float D2 = cost + mn;
      // np.argmin([diag, up, left]) first-min tie-break
      bool tD = (diagD <= upD) && (diagD <= leftD);
      bool tU = (upD <= leftD);
      float pS = tD ? diagS : (tU ? upS : leftS);
      float S2 = cost + pS;
      diagD = leftD; diagS = leftS;
      rowD[i] = D2; rowS[i] = S2;
      upD = D2; upS = S2;
    }
    if (STRIP == 0) bnd[j*64 + tid] = make_float2(rowD[RSTRIP-1], rowS[RSTRIP-1]);
  }
}

__global__ __launch_bounds__(64, 1) void dtwnet_fused(
    const float* __restrict__ x,
    const float* __restrict__ kern,
    const float* __restrict__ W1, const float* __restrict__ b1,
    const float* __restrict__ W2, const float* __restrict__ b2,
    const float* __restrict__ Wl, const float* __restrict__ bl,
    float* __restrict__ out)
{
  __shared__ float klds[NF*KSTRIDE];      // per-filter contiguous, padded stride
  __shared__ float seq_lds[2*NT*PADJ];
  __shared__ float2 bnd[NT*64];           // strip boundary [j][tid], thread-private
  __shared__ float feat_lds[2*NF];
  __shared__ float h1_lds[2*HID];
  __shared__ float h2_lds[2*HID];
  __shared__ float logit_lds[2*NCLS];

  const int tid = threadIdx.x;
  const int bid = blockIdx.x;

  // stage kernels: coalesced global read, near-consecutive LDS write
  for (int d = tid; d < NF*KM*CIN; d += 64) {    // 72 iters
    int f  = d / (KM*CIN);
    int rc = d - f*(KM*CIN);
    klds[f*KSTRIDE + rc] = kern[d];
  }
  // stage 2 sequences, padded to 12 floats per timestep
  for (int d = tid; d < 2*SEQ_LEN; d += 64) {    // 7 iters
    int local = d / SEQ_LEN;
    int r     = d - local*SEQ_LEN;
    int j     = r / CIN;
    int c     = r - j*CIN;
    seq_lds[local*NT*PADJ + j*PADJ + c] = x[bid*(2*SEQ_LEN) + d];
  }
  __syncthreads();

  const int local = tid >> 5;
  const int f     = tid & 31;
  const float* sl = &seq_lds[local*NT*PADJ];
  const float* kl = &klds[f*KSTRIDE];

  float rowD[RSTRIP], rowS[RSTRIP];
  dp_strip<0>(kl, sl, bnd, tid, rowD, rowS);
  dp_strip<1>(kl, sl, bnd, tid, rowD, rowS);

  feat_lds[local*NF + f] = rowS[RSTRIP-1];
  __syncthreads();

  // --- MLP: 32 -> 128 relu -> 128 relu -> 10 softmax (2 seqs / block) ---
  #pragma unroll
  for (int rep = 0; rep < 4; ++rep) {
    int idx = tid + rep*64;        // 0..255
    int sl2 = idx >> 7;
    int j   = idx & (HID-1);
    const float* ft = &feat_lds[sl2*NF];
    float acc = b1[j];
    #pragma unroll
    for (int k = 0; k < NF; ++k) acc = fmaf(ft[k], W1[k*HID + j], acc);
    h1_lds[idx] = fmaxf(acc, 0.f);
  }
  __syncthreads();
  #pragma unroll
  for (int rep = 0; rep < 4; ++rep) {
    int idx = tid + rep*64;
    int sl2 = idx >> 7;
    int j   = idx & (HID-1);
    const float4* hh = (const float4*)&h1_lds[sl2*HID];
    float a0 = b2[j], a1 = 0.f, a2 = 0.f, a3 = 0.f;
    #pragma unroll
    for (int k = 0; k < HID/4; ++k) {
      float4 h4 = hh[k];
      a0 = fmaf(h4.x, W2[(4*k+0)*HID + j], a0);
      a1 = fmaf(h4.y, W2[(4*k+1)*HID + j], a1);
      a2 = fmaf(h4.z, W2[(4*k+2)*HID + j], a2);
      a3 = fmaf(h4.w, W2[(4*k+3)*HID + j], a3);
    }
    h2_lds[idx] = fmaxf((a0 + a1) + (a2 + a3), 0.f);
  }
  __syncthreads();
  if (tid < 2*NCLS) {
    int sl2 = tid / NCLS;
    int j   = tid - sl2*NCLS;
    const float4* hh = (const float4*)&h2_lds[sl2*HID];
    float a0 = bl[j], a1 = 0.f, a2 = 0.f, a3 = 0.f;
    #pragma unroll
    for (int k = 0; k < HID/4; ++k) {
      float4 h4 = hh[k];
      a0 = fmaf(h4.x, Wl[(4*k+0)*NCLS + j], a0);
      a1 = fmaf(h4.y, Wl[(4*k+1)*NCLS + j], a1);
      a2 = fmaf(h4.z, Wl[(4*k+2)*NCLS + j], a2);
      a3 = fmaf(h4.w, Wl[(4*k+3)*NCLS + j], a3);
    }
    logit_lds[tid] = (a0 + a1) + (a2 + a3);
  }
  __syncthreads();
  if (tid < 2) {
    const float* lg = &logit_lds[tid*NCLS];
    float mx = lg[0];
    #pragma unroll
    for (int j = 1; j < NCLS; ++j) mx = fmaxf(mx, lg[j]);
    float e[NCLS]; float sum = 0.f;
    #pragma unroll
    for (int j = 0; j < NCLS; ++j) { e[j] = __expf(lg[j] - mx); sum += e[j]; }
    float inv = 1.f / sum;
    float* op = out + (bid*2 + tid)*NCLS;
    #pragma unroll
    for (int j = 0; j < NCLS; ++j) op[j] = e[j] * inv;
  }
}

extern "C" void kernel_launch(void* const* d_in, const int* in_sizes, int n_in,
                              void* d_out, int out_size, void* d_ws, size_t ws_size,
                              hipStream_t stream) {
  const float* x    = (const float*)d_in[0];
  const float* kern = (const float*)d_in[1];
  const float* W1   = (const float*)d_in[2];
  const float* b1   = (const float*)d_in[3];
  const float* W2   = (const float*)d_in[4];
  const float* b2   = (const float*)d_in[5];
  const float* Wl   = (const float*)d_in[6];
  const float* bl   = (const float*)d_in[7];
  float* out = (float*)d_out;

  dtwnet_fused<<<1024, 64, 0, stream>>>(x, kern, W1, b1, W2, b2, Wl, bl, out);
}

// Round 4
// 89.982 us; speedup vs baseline: 1.2460x; 1.1470x over previous
//
#include <hip/hip_runtime.h>

#define NT   24
#define CIN  9
#define NF   32
#define KM   16
#define HID  128
#define NCLS 10
#define SEQ_LEN (NT*CIN)   // 216
#define PADJ 12            // seq LDS row pitch (floats), 16B-aligned columns
#define NSTRIP 4           // 4 strips of 4 rows; pipelined via shfl

// Thread layout: block = 128 threads = 2 waves, 1 sequence per block.
// lane = strip*16 + f_lo ; filter f = wave*16 + f_lo.
// Strip s computes rows [4s, 4s+4) of the 16x24 DP, skewed: at step t it
// works on column j = t - s. Boundary (row 4s+3) D,S flow to strip s+1
// via __shfl_up(.,16) each step; value shuffled at step t is column t-s,
// consumed by strip s+1 at step t+1 as 'up' and at t+2 as 'diag'.
__global__ __launch_bounds__(128, 4) void dtwnet_fused(
    const float* __restrict__ x,
    const float* __restrict__ kern,
    const float* __restrict__ W1, const float* __restrict__ b1,
    const float* __restrict__ W2, const float* __restrict__ b2,
    const float* __restrict__ Wl, const float* __restrict__ bl,
    float* __restrict__ out)
{
  __shared__ float seq_lds[NT*PADJ];
  __shared__ float feat_lds[NF];
  __shared__ float h1_lds[HID];
  __shared__ float h2_lds[HID];
  __shared__ float logit_lds[NCLS];

  const int tid  = threadIdx.x;
  const int bid  = blockIdx.x;
  const int wave = tid >> 6;
  const int lane = tid & 63;
  const int s    = lane >> 4;       // strip 0..3
  const int f_lo = lane & 15;
  const int f    = wave*16 + f_lo;  // filter 0..31

  // stage this block's sequence (216 floats), padded to 12/timestep
  for (int d = tid; d < SEQ_LEN; d += 128) {
    int jj = d / CIN, cc = d - jj*CIN;
    seq_lds[jj*PADJ + cc] = x[bid*SEQ_LEN + d];
  }
  __syncthreads();

  // filter strip (4 rows x 9 ch = 36 floats) straight from global (L2-hot)
  float kf[4*CIN];
  {
    const float4* kp = (const float4*)(kern + f*(KM*CIN) + s*(4*CIN));
    #pragma unroll
    for (int q = 0; q < 9; ++q) {
      float4 t4 = kp[q];
      kf[4*q+0]=t4.x; kf[4*q+1]=t4.y; kf[4*q+2]=t4.z; kf[4*q+3]=t4.w;
    }
  }

  float rowD[4], rowS[4];
  float bndUpD=0.f, bndUpS=0.f, bndDgD=0.f, bndDgS=0.f;

  #pragma unroll 1
  for (int t = 0; t < NT + NSTRIP - 1; ++t) {
    int j = t - s;                        // this strip's column
    bool active = (j >= 0) && (j < NT);
    float nbD = 0.f, nbS = 0.f;
    if (active) {
      const float4* sp = (const float4*)(seq_lds + j*PADJ);
      float4 q0 = sp[0], q1 = sp[1], q2 = sp[2];
      float sv[CIN] = {q0.x,q0.y,q0.z,q0.w,q1.x,q1.y,q1.z,q1.w,q2.x};
      float cost[4];
      #pragma unroll
      for (int r = 0; r < 4; ++r) {
        float cc = 0.f;
        #pragma unroll
        for (int c = 0; c < CIN; ++c) { float d = kf[r*CIN+c] - sv[c]; cc = fmaf(d, d, cc); }
        cost[r] = cc;
      }
      if (j == 0) {
        // column 0: up-only chain (row 0 starts at 0)
        float accD = (s == 0) ? 0.f : bndUpD;
        float accS = (s == 0) ? 0.f : bndUpS;
        #pragma unroll
        for (int r = 0; r < 4; ++r) { accD += cost[r]; accS += cost[r]; rowD[r]=accD; rowS[r]=accS; }
      } else {
        float upD, upS, diagD, diagS;
        float leftD = rowD[0], leftS = rowS[0];
        float D0, S0;
        if (s == 0) {
          // global row 0: left-only (cumsum)
          D0 = cost[0] + leftD; S0 = cost[0] + leftS;
        } else {
          float mn = fminf(bndDgD, fminf(bndUpD, leftD));
          D0 = cost[0] + mn;
          bool tD = (bndDgD <= bndUpD) && (bndDgD <= leftD);
          bool tU = (bndUpD <= leftD);
          S0 = cost[0] + (tD ? bndDgS : (tU ? bndUpS : leftS));
        }
        diagD = leftD; diagS = leftS;
        rowD[0] = D0; rowS[0] = S0; upD = D0; upS = S0;
        #pragma unroll
        for (int r = 1; r < 4; ++r) {
          float lD = rowD[r], lS = rowS[r];
          float mn = fminf(diagD, fminf(upD, lD));
          float D2 = cost[r] + mn;
          // np.argmin([diag, up, left]) first-min tie-break
          bool tD = (diagD <= upD) && (diagD <= lD);
          bool tU = (upD <= lD);
          float S2 = cost[r] + (tD ? diagS : (tU ? upS : lS));
          diagD = lD; diagS = lS;
          rowD[r] = D2; rowS[r] = S2; upD = D2; upS = S2;
        }
      }
      nbD = rowD[3]; nbS = rowS[3];
    }
    // wave-wide boundary hand-off to the next strip
    float rD = __shfl_up(nbD, 16u);
    float rS = __shfl_up(nbS, 16u);
    bndDgD = bndUpD; bndDgS = bndUpS;
    bndUpD = rD;     bndUpS = rS;
  }

  if (s == 3) feat_lds[f] = rowS[3];
  __syncthreads();

  // --- MLP: 32 -> 128 relu -> 128 relu -> 10 softmax (1 seq / block) ---
  {
    float acc = b1[tid];
    #pragma unroll
    for (int k = 0; k < NF; ++k) acc = fmaf(feat_lds[k], W1[k*HID + tid], acc);
    h1_lds[tid] = fmaxf(acc, 0.f);
  }
  __syncthreads();
  {
    const float4* hh = (const float4*)h1_lds;
    float a0 = b2[tid], a1 = 0.f, a2 = 0.f, a3 = 0.f;
    #pragma unroll
    for (int k = 0; k < HID/4; ++k) {
      float4 h4 = hh[k];
      a0 = fmaf(h4.x, W2[(4*k+0)*HID + tid], a0);
      a1 = fmaf(h4.y, W2[(4*k+1)*HID + tid], a1);
      a2 = fmaf(h4.z, W2[(4*k+2)*HID + tid], a2);
      a3 = fmaf(h4.w, W2[(4*k+3)*HID + tid], a3);
    }
    h2_lds[tid] = fmaxf((a0 + a1) + (a2 + a3), 0.f);
  }
  __syncthreads();
  if (tid < NCLS) {
    const float4* hh = (const float4*)h2_lds;
    float a0 = bl[tid], a1 = 0.f, a2 = 0.f, a3 = 0.f;
    #pragma unroll
    for (int k = 0; k < HID/4; ++k) {
      float4 h4 = hh[k];
      a0 = fmaf(h4.x, Wl[(4*k+0)*NCLS + tid], a0);
      a1 = fmaf(h4.y, Wl[(4*k+1)*NCLS + tid], a1);
      a2 = fmaf(h4.z, Wl[(4*k+2)*NCLS + tid], a2);
      a3 = fmaf(h4.w, Wl[(4*k+3)*NCLS + tid], a3);
    }
    logit_lds[tid] = (a0 + a1) + (a2 + a3);
  }
  __syncthreads();
  if (tid == 0) {
    float mx = logit_lds[0];
    #pragma unroll
    for (int j = 1; j < NCLS; ++j) mx = fmaxf(mx, logit_lds[j]);
    float e[NCLS]; float sum = 0.f;
    #pragma unroll
    for (int j = 0; j < NCLS; ++j) { e[j] = __expf(logit_lds[j] - mx); sum += e[j]; }
    float inv = 1.f / sum;
    float* op = out + bid*NCLS;
    #pragma unroll
    for (int j = 0; j < NCLS; ++j) op[j] = e[j] * inv;
  }
}

extern "C" void kernel_launch(void* const* d_in, const int* in_sizes, int n_in,
                              void* d_out, int out_size, void* d_ws, size_t ws_size,
                              hipStream_t stream) {
  const float* x    = (const float*)d_in[0];
  const float* kern = (const float*)d_in[1];
  const float* W1   = (const float*)d_in[2];
  const float* b1   = (const float*)d_in[3];
  const float* W2   = (const float*)d_in[4];
  const float* b2   = (const float*)d_in[5];
  const float* Wl   = (const float*)d_in[6];
  const float* bl   = (const float*)d_in[7];
  float* out = (float*)d_out;

  dtwnet_fused<<<2048, 128, 0, stream>>>(x, kern, W1, b1, W2, b2, Wl, bl, out);
}

// Round 5
// 86.950 us; speedup vs baseline: 1.2895x; 1.0349x over previous
//
#include <hip/hip_runtime.h>

#define NT   24
#define CIN  9
#define NF   32
#define KM   16
#define HID  128
#define NCLS 10
#define SEQ_LEN (NT*CIN)   // 216
#define PADJ 12            // seq LDS row pitch (floats), 16B-aligned columns
#define NSTRIP 4           // 4 strips of 4 rows; pipelined via shfl

// KEY IDENTITY: D[m-1,n-1] (forward DTW) == backtracked path-cost sum.
// The backtrack picks argmin over the same D-values the forward min uses,
// so the local costs telescope; only fp summation ORDER differs (forward
// vs reverse), which is ~1e-6 relative — far below the 2e-2 threshold.
// So the S (path-sum) chain is dropped entirely.
//
// Thread layout: block = 128 threads = 2 waves, 1 sequence per block.
// lane = strip*16 + f_lo ; filter f = wave*16 + f_lo.
// Strip s computes rows [4s, 4s+4), skewed: at step t it works column
// j = t - s. Row-boundary D flows strip s -> s+1 via __shfl_up(.,16);
// the value shuffled at step t (column t-s) is consumed at t+1 as 'up'
// and at t+2 as 'diag'.
__global__ __launch_bounds__(128, 4) void dtwnet_fused(
    const float* __restrict__ x,
    const float* __restrict__ kern,
    const float* __restrict__ W1, const float* __restrict__ b1,
    const float* __restrict__ W2, const float* __restrict__ b2,
    const float* __restrict__ Wl, const float* __restrict__ bl,
    float* __restrict__ out)
{
  __shared__ float seq_lds[NT*PADJ];
  __shared__ float feat_lds[NF];
  __shared__ float h1_lds[HID];
  __shared__ float h2_lds[HID];
  __shared__ float logit_lds[NCLS];

  const int tid  = threadIdx.x;
  const int bid  = blockIdx.x;
  const int wave = tid >> 6;
  const int lane = tid & 63;
  const int s    = lane >> 4;       // strip 0..3
  const int f_lo = lane & 15;
  const int f    = wave*16 + f_lo;  // filter 0..31

  // filter strip (4 rows x 9 ch) straight from global (L2-hot) — issue
  // BEFORE the barrier so the loads overlap seq staging + sync.
  float kf[4*CIN];
  {
    const float4* kp = (const float4*)(kern + f*(KM*CIN) + s*(4*CIN));
    float4 t0 = kp[0], t1 = kp[1], t2 = kp[2], t3 = kp[3], t4 = kp[4],
           t5 = kp[5], t6 = kp[6], t7 = kp[7], t8 = kp[8];
    kf[0]=t0.x; kf[1]=t0.y; kf[2]=t0.z; kf[3]=t0.w;
    kf[4]=t1.x; kf[5]=t1.y; kf[6]=t1.z; kf[7]=t1.w;
    kf[8]=t2.x; kf[9]=t2.y; kf[10]=t2.z; kf[11]=t2.w;
    kf[12]=t3.x; kf[13]=t3.y; kf[14]=t3.z; kf[15]=t3.w;
    kf[16]=t4.x; kf[17]=t4.y; kf[18]=t4.z; kf[19]=t4.w;
    kf[20]=t5.x; kf[21]=t5.y; kf[22]=t5.z; kf[23]=t5.w;
    kf[24]=t6.x; kf[25]=t6.y; kf[26]=t6.z; kf[27]=t6.w;
    kf[28]=t7.x; kf[29]=t7.y; kf[30]=t7.z; kf[31]=t7.w;
    kf[32]=t8.x; kf[33]=t8.y; kf[34]=t8.z; kf[35]=t8.w;
  }

  // stage this block's sequence (216 floats), padded to 12/timestep
  for (int d = tid; d < SEQ_LEN; d += 128) {
    int jj = d / CIN, cc = d - jj*CIN;
    seq_lds[jj*PADJ + cc] = x[bid*SEQ_LEN + d];
  }
  __syncthreads();

  float rowD[4];
  float bndUp = 0.f, bndDg = 0.f;

  #pragma unroll 1
  for (int t = 0; t < NT + NSTRIP - 1; ++t) {
    int j = t - s;                        // this strip's column
    bool active = (j >= 0) && (j < NT);
    float nb = 0.f;
    if (active) {
      const float4* sp = (const float4*)(seq_lds + j*PADJ);
      float4 q0 = sp[0], q1 = sp[1], q2 = sp[2];
      float sv[CIN] = {q0.x,q0.y,q0.z,q0.w,q1.x,q1.y,q1.z,q1.w,q2.x};
      float cost[4];
      #pragma unroll
      for (int r = 0; r < 4; ++r) {
        float cc = 0.f;
        #pragma unroll
        for (int c = 0; c < CIN; ++c) { float d = kf[r*CIN+c] - sv[c]; cc = fmaf(d, d, cc); }
        cost[r] = cc;
      }
      if (j == 0) {
        // column 0: up-only chain (row 0 starts at 0)
        float acc = (s == 0) ? 0.f : bndUp;
        #pragma unroll
        for (int r = 0; r < 4; ++r) { acc += cost[r]; rowD[r] = acc; }
      } else {
        float up, diag;
        float left = rowD[0];
        float D0;
        if (s == 0) {
          D0 = cost[0] + left;                       // global row 0: left-only
        } else {
          D0 = cost[0] + fminf(bndDg, fminf(bndUp, left));
        }
        diag = left;
        rowD[0] = D0; up = D0;
        #pragma unroll
        for (int r = 1; r < 4; ++r) {
          float lD = rowD[r];
          float D2 = cost[r] + fminf(diag, fminf(up, lD));
          diag = lD;
          rowD[r] = D2; up = D2;
        }
      }
      nb = rowD[3];
    }
    // wave-wide boundary hand-off to the next strip
    float rD = __shfl_up(nb, 16u);
    bndDg = bndUp;
    bndUp = rD;
  }

  if (s == 3) feat_lds[f] = rowD[3];
  __syncthreads();

  // --- MLP: 32 -> 128 relu -> 128 relu -> 10 softmax (1 seq / block) ---
  {
    float acc = b1[tid];
    #pragma unroll
    for (int k = 0; k < NF; ++k) acc = fmaf(feat_lds[k], W1[k*HID + tid], acc);
    h1_lds[tid] = fmaxf(acc, 0.f);
  }
  __syncthreads();
  {
    const float4* hh = (const float4*)h1_lds;
    float a0 = b2[tid], a1 = 0.f, a2 = 0.f, a3 = 0.f;
    #pragma unroll
    for (int k = 0; k < HID/4; ++k) {
      float4 h4 = hh[k];
      a0 = fmaf(h4.x, W2[(4*k+0)*HID + tid], a0);
      a1 = fmaf(h4.y, W2[(4*k+1)*HID + tid], a1);
      a2 = fmaf(h4.z, W2[(4*k+2)*HID + tid], a2);
      a3 = fmaf(h4.w, W2[(4*k+3)*HID + tid], a3);
    }
    h2_lds[tid] = fmaxf((a0 + a1) + (a2 + a3), 0.f);
  }
  __syncthreads();
  if (tid < NCLS) {
    const float4* hh = (const float4*)h2_lds;
    float a0 = bl[tid], a1 = 0.f, a2 = 0.f, a3 = 0.f;
    #pragma unroll
    for (int k = 0; k < HID/4; ++k) {
      float4 h4 = hh[k];
      a0 = fmaf(h4.x, Wl[(4*k+0)*NCLS + tid], a0);
      a1 = fmaf(h4.y, Wl[(4*k+1)*NCLS + tid], a1);
      a2 = fmaf(h4.z, Wl[(4*k+2)*NCLS + tid], a2);
      a3 = fmaf(h4.w, Wl[(4*k+3)*NCLS + tid], a3);
    }
    logit_lds[tid] = (a0 + a1) + (a2 + a3);
  }
  __syncthreads();
  if (tid == 0) {
    float mx = logit_lds[0];
    #pragma unroll
    for (int j = 1; j < NCLS; ++j) mx = fmaxf(mx, logit_lds[j]);
    float e[NCLS]; float sum = 0.f;
    #pragma unroll
    for (int j = 0; j < NCLS; ++j) { e[j] = __expf(logit_lds[j] - mx); sum += e[j]; }
    float inv = 1.f / sum;
    float* op = out + bid*NCLS;
    #pragma unroll
    for (int j = 0; j < NCLS; ++j) op[j] = e[j] * inv;
  }
}

extern "C" void kernel_launch(void* const* d_in, const int* in_sizes, int n_in,
                              void* d_out, int out_size, void* d_ws, size_t ws_size,
                              hipStream_t stream) {
  const float* x    = (const float*)d_in[0];
  const float* kern = (const float*)d_in[1];
  const float* W1   = (const float*)d_in[2];
  const float* b1   = (const float*)d_in[3];
  const float* W2   = (const float*)d_in[4];
  const float* b2   = (const float*)d_in[5];
  const float* Wl   = (const float*)d_in[6];
  const float* bl   = (const float*)d_in[7];
  float* out = (float*)d_out;

  dtwnet_fused<<<2048, 128, 0, stream>>>(x, kern, W1, b1, W2, b2, Wl, bl, out);
}

// Round 6
// 84.000 us; speedup vs baseline: 1.3348x; 1.0351x over previous
//
#include <hip/hip_runtime.h>

#define NT   24
#define CIN  9
#define NF   32
#define KM   16
#define HID  128
#define NCLS 10
#define SEQ_LEN (NT*CIN)   // 216
#define PADJ 12            // seq LDS row pitch (floats), 16B-aligned columns
#define NSTRIP 4           // 4 strips of 4 rows; pipelined via shfl

// D[m-1,n-1] (forward DTW) == backtracked path-cost sum (telescoping; only fp
// summation order differs). Cost uses the quadratic expansion:
//   ||k-x||^2 = ||k||^2 + ||x||^2 - 2 k.x
// with kf pre-scaled by -2 and the accumulator seeded with a[r]+b[j]:
// per cell = 1 add + 9 fma (vs 9 sub + 9 fma direct). D is min-plus in the
// costs, so near-tie path flips do not perturb D — expansion noise (~1e-5)
// passes straight through to the features.
//
// Thread layout: block = 128 threads = 2 waves, 1 sequence per block.
// lane = strip*16 + f_lo ; filter f = wave*16 + f_lo.
// Strip s computes rows [4s,4s+4), skewed: step t works column j = t-s.
// Boundary D flows strip s -> s+1 via __shfl_up(.,16).
__global__ __launch_bounds__(128, 4) void dtwnet_fused(
    const float* __restrict__ x,
    const float* __restrict__ kern,
    const float* __restrict__ W1, const float* __restrict__ b1,
    const float* __restrict__ W2, const float* __restrict__ b2,
    const float* __restrict__ Wl, const float* __restrict__ bl,
    float* __restrict__ out)
{
  __shared__ float seq_lds[NT*PADJ];
  __shared__ float bcol[NT];          // ||x_j||^2 per column
  __shared__ float feat_lds[NF];
  __shared__ float h1_lds[HID];
  __shared__ float h2_lds[HID];
  __shared__ float logit_lds[NCLS];

  const int tid  = threadIdx.x;
  const int bid  = blockIdx.x;
  const int wave = tid >> 6;
  const int lane = tid & 63;
  const int s    = lane >> 4;       // strip 0..3
  const int f_lo = lane & 15;
  const int f    = wave*16 + f_lo;  // filter 0..31

  // filter strip (4 rows x 9 ch) from global (L2-hot), issued pre-barrier
  float kf[4*CIN];
  {
    const float4* kp = (const float4*)(kern + f*(KM*CIN) + s*(4*CIN));
    float4 t0 = kp[0], t1 = kp[1], t2 = kp[2], t3 = kp[3], t4 = kp[4],
           t5 = kp[5], t6 = kp[6], t7 = kp[7], t8 = kp[8];
    kf[0]=t0.x; kf[1]=t0.y; kf[2]=t0.z; kf[3]=t0.w;
    kf[4]=t1.x; kf[5]=t1.y; kf[6]=t1.z; kf[7]=t1.w;
    kf[8]=t2.x; kf[9]=t2.y; kf[10]=t2.z; kf[11]=t2.w;
    kf[12]=t3.x; kf[13]=t3.y; kf[14]=t3.z; kf[15]=t3.w;
    kf[16]=t4.x; kf[17]=t4.y; kf[18]=t4.z; kf[19]=t4.w;
    kf[20]=t5.x; kf[21]=t5.y; kf[22]=t5.z; kf[23]=t5.w;
    kf[24]=t6.x; kf[25]=t6.y; kf[26]=t6.z; kf[27]=t6.w;
    kf[28]=t7.x; kf[29]=t7.y; kf[30]=t7.z; kf[31]=t7.w;
    kf[32]=t8.x; kf[33]=t8.y; kf[34]=t8.z; kf[35]=t8.w;
  }

  // stage this block's sequence (216 floats), padded to 12/timestep
  for (int d = tid; d < SEQ_LEN; d += 128) {
    int jj = d / CIN, cc = d - jj*CIN;
    seq_lds[jj*PADJ + cc] = x[bid*SEQ_LEN + d];
  }
  __syncthreads();

  // column norms ||x_j||^2 (24 values, one thread each)
  if (tid < NT) {
    const float4* sp = (const float4*)(seq_lds + tid*PADJ);
    float4 q0 = sp[0], q1 = sp[1], q2 = sp[2];
    float b = q0.x*q0.x + q0.y*q0.y + q0.z*q0.z + q0.w*q0.w
            + q1.x*q1.x + q1.y*q1.y + q1.z*q1.z + q1.w*q1.w
            + q2.x*q2.x;
    bcol[tid] = b;
  }

  // a[r] = ||k_r||^2, then pre-scale kf by -2
  float arow[4];
  #pragma unroll
  for (int r = 0; r < 4; ++r) {
    float a = 0.f;
    #pragma unroll
    for (int c = 0; c < CIN; ++c) a = fmaf(kf[r*CIN+c], kf[r*CIN+c], a);
    arow[r] = a;
  }
  #pragma unroll
  for (int q = 0; q < 4*CIN; ++q) kf[q] *= -2.f;
  __syncthreads();

  float rowD[4];
  float bndUp = 0.f, bndDg = 0.f;

  #pragma unroll 1
  for (int t = 0; t < NT + NSTRIP - 1; ++t) {
    int j = t - s;                        // this strip's column
    bool active = (j >= 0) && (j < NT);
    float nb = 0.f;
    if (active) {
      const float4* sp = (const float4*)(seq_lds + j*PADJ);
      float4 q0 = sp[0], q1 = sp[1], q2 = sp[2];
      float bj = bcol[j];
      float sv[CIN] = {q0.x,q0.y,q0.z,q0.w,q1.x,q1.y,q1.z,q1.w,q2.x};
      float cost[4];
      #pragma unroll
      for (int r = 0; r < 4; ++r) {
        float cc = arow[r] + bj;
        #pragma unroll
        for (int c = 0; c < CIN; ++c) cc = fmaf(kf[r*CIN+c], sv[c], cc);
        cost[r] = cc;
      }
      if (j == 0) {
        // column 0: up-only chain (row 0 starts at 0)
        float acc = (s == 0) ? 0.f : bndUp;
        #pragma unroll
        for (int r = 0; r < 4; ++r) { acc += cost[r]; rowD[r] = acc; }
      } else {
        float up, diag;
        float left = rowD[0];
        float D0;
        if (s == 0) {
          D0 = cost[0] + left;                       // global row 0: left-only
        } else {
          D0 = cost[0] + fminf(bndDg, fminf(bndUp, left));
        }
        diag = left;
        rowD[0] = D0; up = D0;
        #pragma unroll
        for (int r = 1; r < 4; ++r) {
          float lD = rowD[r];
          float D2 = cost[r] + fminf(diag, fminf(up, lD));
          diag = lD;
          rowD[r] = D2; up = D2;
        }
      }
      nb = rowD[3];
    }
    // wave-wide boundary hand-off to the next strip
    float rD = __shfl_up(nb, 16u);
    bndDg = bndUp;
    bndUp = rD;
  }

  if (s == 3) feat_lds[f] = rowD[3];
  __syncthreads();

  // --- MLP: 32 -> 128 relu -> 128 relu -> 10 softmax (1 seq / block) ---
  {
    float acc = b1[tid];
    #pragma unroll
    for (int k = 0; k < NF; ++k) acc = fmaf(feat_lds[k], W1[k*HID + tid], acc);
    h1_lds[tid] = fmaxf(acc, 0.f);
  }
  __syncthreads();
  {
    const float4* hh = (const float4*)h1_lds;
    float a0 = b2[tid], a1 = 0.f, a2 = 0.f, a3 = 0.f;
    #pragma unroll
    for (int k = 0; k < HID/4; ++k) {
      float4 h4 = hh[k];
      a0 = fmaf(h4.x, W2[(4*k+0)*HID + tid], a0);
      a1 = fmaf(h4.y, W2[(4*k+1)*HID + tid], a1);
      a2 = fmaf(h4.z, W2[(4*k+2)*HID + tid], a2);
      a3 = fmaf(h4.w, W2[(4*k+3)*HID + tid], a3);
    }
    h2_lds[tid] = fmaxf((a0 + a1) + (a2 + a3), 0.f);
  }
  __syncthreads();
  if (tid < NCLS) {
    const float4* hh = (const float4*)h2_lds;
    float a0 = bl[tid], a1 = 0.f, a2 = 0.f, a3 = 0.f;
    #pragma unroll
    for (int k = 0; k < HID/4; ++k) {
      float4 h4 = hh[k];
      a0 = fmaf(h4.x, Wl[(4*k+0)*NCLS + tid], a0);
      a1 = fmaf(h4.y, Wl[(4*k+1)*NCLS + tid], a1);
      a2 = fmaf(h4.z, Wl[(4*k+2)*NCLS + tid], a2);
      a3 = fmaf(h4.w, Wl[(4*k+3)*NCLS + tid], a3);
    }
    logit_lds[tid] = (a0 + a1) + (a2 + a3);
  }
  __syncthreads();
  if (tid == 0) {
    float mx = logit_lds[0];
    #pragma unroll
    for (int j = 1; j < NCLS; ++j) mx = fmaxf(mx, logit_lds[j]);
    float e[NCLS]; float sum = 0.f;
    #pragma unroll
    for (int j = 0; j < NCLS; ++j) { e[j] = __expf(logit_lds[j] - mx); sum += e[j]; }
    float inv = 1.f / sum;
    float* op = out + bid*NCLS;
    #pragma unroll
    for (int j = 0; j < NCLS; ++j) op[j] = e[j] * inv;
  }
}

extern "C" void kernel_launch(void* const* d_in, const int* in_sizes, int n_in,
                              void* d_out, int out_size, void* d_ws, size_t ws_size,
                              hipStream_t stream) {
  const float* x    = (const float*)d_in[0];
  const float* kern = (const float*)d_in[1];
  const float* W1   = (const float*)d_in[2];
  const float* b1   = (const float*)d_in[3];
  const float* W2   = (const float*)d_in[4];
  const float* b2   = (const float*)d_in[5];
  const float* Wl   = (const float*)d_in[6];
  const float* bl   = (const float*)d_in[7];
  float* out = (float*)d_out;

  dtwnet_fused<<<2048, 128, 0, stream>>>(x, kern, W1, b1, W2, b2, Wl, bl, out);
}